// Round 3
// baseline (51368.036 us; speedup 1.0000x reference)
//
#include <hip/hip_runtime.h>
#include <hip/hip_fp16.h>

#define TT 16384
#define HID 256
#define EMBD 16
#define TMPD 128
#define VOC 2048
#define NWG 32          // 32 single-wave workgroups
#define RPW 64          // rows per wave (1 row per lane)

typedef unsigned long long u64;
typedef unsigned int u32;
typedef unsigned short u16;

// workspace layout (bytes)
#define U_OFF_B    0ull                      // 16384*128*4 = 8 MiB
#define C_OFF_B    8388608ull                // 2048*128*4  = 1 MiB
#define SLOT_OFF_B 9437184ull                // 16384*32*8  = 4 MiB
#define TAG 0x15ull                          // 10101b: != poison(01010b), != 0

// ---------------------------------------------------------------------------
// Phase A: U[t] = b1 + W1[:, :256] @ x_t   (blocks 0..TT-1)
//          C[i] = W1[:, 256:272] @ emb[i]  (blocks TT..TT+VOC-1)
// Zero-inits every per-step slot (tag check fails on 0 and on 0xAA poison).
// ---------------------------------------------------------------------------
__global__ __launch_bounds__(128) void prep_kernel(
    const float* __restrict__ x, const float* __restrict__ emb,
    const float* __restrict__ W1, const float* __restrict__ b1,
    float* __restrict__ U, float* __restrict__ C, u64* __restrict__ slots)
{
  const int b = blockIdx.x;
  const int j = threadIdx.x;   // 0..127 = output feature
  if (b < TT) {
    __shared__ __align__(16) float xs[HID];
    if (j < HID / 4) ((float4*)xs)[j] = ((const float4*)(x + (size_t)b * HID))[j];
    if (j < NWG) slots[(size_t)b * NWG + j] = 0ull;
    __syncthreads();
    float acc = b1[j];
    const float4* wr = (const float4*)(W1 + (size_t)j * (HID + EMBD)); // 1088B rows, 16B aligned
    #pragma unroll 8
    for (int c = 0; c < HID / 4; ++c) {
      float4 w = wr[c];
      acc = fmaf(xs[4 * c + 0], w.x, acc);
      acc = fmaf(xs[4 * c + 1], w.y, acc);
      acc = fmaf(xs[4 * c + 2], w.z, acc);
      acc = fmaf(xs[4 * c + 3], w.w, acc);
    }
    U[(size_t)b * TMPD + j] = acc;
  } else {
    const int e = b - TT;
    const float* er = emb + (size_t)e * EMBD;
    const float* wr = W1 + (size_t)j * (HID + EMBD) + HID;
    float acc = 0.f;
    #pragma unroll
    for (int k = 0; k < EMBD; ++k) acc = fmaf(er[k], wr[k], acc);
    C[(size_t)e * TMPD + j] = acc;
  }
}

// ---------------------------------------------------------------------------
// Phase B: 32 autonomous single-wave workgroups, 64 W2 rows each (1/lane,
// 128 fp32 in regs). Per step: h = lrelu(U[t]+C[cur]) via private LDS copy;
// per-lane dot (order bit-identical to the verified round-2 kernel); in-wave
// butterfly (max + f16-packed sumexp); lane0 publishes ONE u64 slot; all
// lanes poll the 32 slots with one coalesced load/iter; LDS-bounce + VALU
// scan gives argmax (u64 max => np first-index tie-break) and logsumexp.
// Key: [63:32] ord(maxlogit) | [31:21] 2047-row | [20:5] f16(sumexp) | [4:0] TAG
// ---------------------------------------------------------------------------
__global__ __launch_bounds__(64, 1) void seq_kernel(
    const float* __restrict__ emb, const float* __restrict__ W2,
    const float* __restrict__ b2v, const int* __restrict__ init_idx,
    const float* __restrict__ U, const float* __restrict__ C,
    u64* slots,
    float* __restrict__ out0, float* __restrict__ out1,
    float* __restrict__ out2)
{
  const int g = blockIdx.x;
  const int lane = threadIdx.x;          // 0..63
  const int row = (g << 6) | lane;       // this lane's W2 row

  // W2 row -> 128 fp32 regs (unified VGPR/AGPR file; no spill at LB(64,1))
  float w[TMPD];
  {
    const float4* wr = (const float4*)(W2 + (size_t)row * TMPD);
    #pragma unroll
    for (int c = 0; c < TMPD / 4; ++c) {
      float4 v = wr[c];
      w[4 * c + 0] = v.x; w[4 * c + 1] = v.y; w[4 * c + 2] = v.z; w[4 * c + 3] = v.w;
    }
  }
  const float br = b2v[row];

  __shared__ __align__(16) float hbuf[TMPD];   // this wave's private h copy
  __shared__ __align__(16) u64 kbuf[NWG];      // slot bounce

  int cur = init_idx[0];
  // software-pipelined carries
  float2 u2 = *(const float2*)(U + 2 * lane);                       // U[0]
  float2 c2 = *(const float2*)(C + (size_t)cur * TMPD + 2 * lane);  // C[init]
  float2 e2 = {0.f, 0.f};                                           // out1 pipeline (wg0, lane<8)

  for (int t = 0; t < TT; ++t) {
    // h = leaky_relu(U[t] + C[cur]); each lane owns h[2*lane .. 2*lane+1]
    float hx = u2.x + c2.x, hy = u2.y + c2.y;
    float2 h2 = { (hx > 0.f) ? hx : 0.01f * hx,
                  (hy > 0.f) ? hy : 0.01f * hy };
    *(float2*)(hbuf + 2 * lane) = h2;
    // prefetch next U row (pure stream, independent of feedback)
    u2 = *(const float2*)(U + (size_t)(t + 1) * TMPD + 2 * lane);
    __syncthreads();                     // single-wave: cheap; orders LDS

    // logit = b2[row] + w . h   (k-order identical to round-2 kernel)
    float acc = br;
    #pragma unroll
    for (int k0 = 0; k0 < TMPD; k0 += 4) {
      float4 hv = *(const float4*)(hbuf + k0);   // ds_read_b128 broadcast
      acc = fmaf(w[k0 + 0], hv.x, acc);
      acc = fmaf(w[k0 + 1], hv.y, acc);
      acc = fmaf(w[k0 + 2], hv.z, acc);
      acc = fmaf(w[k0 + 3], hv.w, acc);
    }
    float s = __expf(acc);

    // in-wave butterfly: max logit + partial sumexp (independent chains)
    float m = acc, S = s;
    #pragma unroll
    for (int off = 1; off < 64; off <<= 1) {
      m = fmaxf(m, __shfl_xor(m, off));
      S += __shfl_xor(S, off);
    }
    const u64 bal = __ballot(acc == m);          // winners; lowest lane = lowest row
    const int win = __ffsll(bal) - 1;
    const int wrow = (g << 6) | win;

    u32 fb  = __float_as_uint(m);
    u32 ord = (fb & 0x80000000u) ? ~fb : (fb | 0x80000000u);
    u64 key = ((u64)ord << 32) | ((u64)(u32)(2047 - wrow) << 21)
            | ((u64)__half_as_ushort(__float2half(S)) << 5) | TAG;

    u64* base = slots + (size_t)t * NWG;
    if (lane == 0)
      __hip_atomic_store(base + g, key, __ATOMIC_RELAXED, __HIP_MEMORY_SCOPE_AGENT);

    // coalesced poll: lane q watches slot (q&31); one 256B wave-load per iter
    u64 kq;
    do {
      kq = __hip_atomic_load(base + (lane & 31), __ATOMIC_RELAXED, __HIP_MEMORY_SCOPE_AGENT);
    } while (!__all((int)((kq & 0x1Full) == TAG)));

    if (lane < NWG) kbuf[lane] = kq;
    __syncthreads();                     // bounce -> every lane scans in VALU

    u64 best = kbuf[0];
    #pragma unroll
    for (int q = 1; q < NWG; ++q) { u64 k = kbuf[q]; if (k > best) best = k; }
    const int nidx = 2047 - (int)((best >> 21) & 0x7FF);

    // issue next-step C load NOW; Σ/log/out0 tail overlaps its latency
    c2 = *(const float2*)(C + (size_t)nidx * TMPD + 2 * lane);

    float Sp = 0.f;
    #pragma unroll
    for (int q = 0; q < NWG; ++q)
      Sp += __half2float(__ushort_as_half((u16)((kbuf[q] >> 5) & 0xFFFFull)));
    const float lgS = __logf(Sp);

    out0[(size_t)t * VOC + row] = acc - lgS;

    if (g == 0) {
      if (lane < EMBD / 2) {
        if (t) *(float2*)(out1 + (size_t)(t - 1) * EMBD + 2 * lane) = e2;  // drained last step
        e2 = *(const float2*)(emb + (size_t)nidx * EMBD + 2 * lane);       // drains this step
      }
      if (lane == 0) out2[t] = (float)nidx;
    }
    cur = nidx;
  }
  if (g == 0 && lane < EMBD / 2)
    *(float2*)(out1 + (size_t)(TT - 1) * EMBD + 2 * lane) = e2;
}

// ---------------------------------------------------------------------------
extern "C" void kernel_launch(void* const* d_in, const int* in_sizes, int n_in,
                              void* d_out, int out_size, void* d_ws, size_t ws_size,
                              hipStream_t stream) {
  const float* x    = (const float*)d_in[0];   // [16384,256] f32
  const float* emb  = (const float*)d_in[1];   // [2048,16]   f32
  const float* W1   = (const float*)d_in[2];   // [128,272]   f32
  const float* b1   = (const float*)d_in[3];   // [128]       f32
  const float* W2   = (const float*)d_in[4];   // [2048,128]  f32
  const float* b2v  = (const float*)d_in[5];   // [2048]      f32
  const int*   init = (const int*)d_in[6];     // scalar int

  float* U    = (float*)((char*)d_ws + U_OFF_B);
  float* C    = (float*)((char*)d_ws + C_OFF_B);
  u64*   slot = (u64*)((char*)d_ws + SLOT_OFF_B);

  float* out0 = (float*)d_out;                                        // [T, 2048]
  float* out1 = (float*)d_out + (size_t)TT * VOC;                     // [T, 1, 16]
  float* out2 = (float*)d_out + (size_t)TT * VOC + (size_t)TT * EMBD; // [T]

  hipLaunchKernelGGL(prep_kernel, dim3(TT + VOC), dim3(128), 0, stream,
                     x, emb, W1, b1, U, C, slot);
  hipLaunchKernelGGL(seq_kernel, dim3(NWG), dim3(64), 0, stream,
                     emb, W2, b2v, init, U, C, slot, out0, out1, out2);
}

// Round 4
// 45628.488 us; speedup vs baseline: 1.1258x; 1.1258x over previous
//
#include <hip/hip_runtime.h>
#include <hip/hip_fp16.h>

#define TT 16384
#define HID 256
#define EMBD 16
#define TMPD 128
#define VOC 2048
#define NG 8            // 8 workgroups
#define WPG 4           // 4 waves (256 threads) each; 256 rows per wg, 1 row/lane

typedef unsigned long long u64;
typedef unsigned int u32;
typedef unsigned short u16;

// workspace layout (bytes)
#define U_OFF_B    0ull                      // 16384*128*4 = 8 MiB
#define C_OFF_B    8388608ull                // 2048*128*4  = 1 MiB
#define SLOT_OFF_B 9437184ull                // 16384*8*8   = 1 MiB

// per-step parity tag: != 0 (prep zero-init), != 0x0A (0xAA poison low5)
__device__ __forceinline__ u64 tag_of(int t) { return (t & 1) ? 0x0Bull : 0x15ull; }

// ---------------------------------------------------------------------------
// Phase A: U[t] = b1 + W1[:, :256] @ x_t   (blocks 0..TT-1)
//          C[i] = W1[:, 256:272] @ emb[i]  (blocks TT..TT+VOC-1)
// Zero-inits every per-step slot.
// ---------------------------------------------------------------------------
__global__ __launch_bounds__(128) void prep_kernel(
    const float* __restrict__ x, const float* __restrict__ emb,
    const float* __restrict__ W1, const float* __restrict__ b1,
    float* __restrict__ U, float* __restrict__ C, u64* __restrict__ slots)
{
  const int b = blockIdx.x;
  const int j = threadIdx.x;   // 0..127 = output feature
  if (b < TT) {
    __shared__ __align__(16) float xs[HID];
    if (j < HID / 4) ((float4*)xs)[j] = ((const float4*)(x + (size_t)b * HID))[j];
    if (j < NG) slots[(size_t)b * NG + j] = 0ull;
    __syncthreads();
    float acc = b1[j];
    const float4* wr = (const float4*)(W1 + (size_t)j * (HID + EMBD)); // 1088B rows, 16B aligned
    #pragma unroll 8
    for (int c = 0; c < HID / 4; ++c) {
      float4 w = wr[c];
      acc = fmaf(xs[4 * c + 0], w.x, acc);
      acc = fmaf(xs[4 * c + 1], w.y, acc);
      acc = fmaf(xs[4 * c + 2], w.z, acc);
      acc = fmaf(xs[4 * c + 3], w.w, acc);
    }
    U[(size_t)b * TMPD + j] = acc;
  } else {
    const int e = b - TT;
    const float* er = emb + (size_t)e * EMBD;
    const float* wr = W1 + (size_t)j * (HID + EMBD) + HID;
    float acc = 0.f;
    #pragma unroll
    for (int k = 0; k < EMBD; ++k) acc = fmaf(er[k], wr[k], acc);
    C[(size_t)e * TMPD + j] = acc;
  }
}

// ---------------------------------------------------------------------------
// Phase B: 8 wgs x 4 waves, 1 W2 row/lane (128 fp32 regs). NO s_barrier in
// the hot loop:
//   - per-wave private hbuf (wave-internal LDS is FIFO ordered)
//   - intra-wg combine: waves drop tagged keys in LDS; wave0 polls+combines,
//     publishes wg key to the step's 64B global slot line; waves 1-3 go
//     straight to the global poll
//   - global poll: lane q watches slot q&7 (one coalesced load/iter),
//     __all on tag; then 3x shfl_xor max scan -> every lane has the winner
//   - C[nidx] load issued right after the max scan; logsumexp/out0 overlap it
// Key: [63:32] ord(maxlogit) | [31:21] 2047-row | [20:5] f16(sumexp) | [4:0] tag
// ---------------------------------------------------------------------------
__global__ __launch_bounds__(256, 1) void seq_kernel(
    const float* __restrict__ emb, const float* __restrict__ W2,
    const float* __restrict__ b2v, const int* __restrict__ init_idx,
    const float* __restrict__ U, const float* __restrict__ C,
    u64* slots,
    float* __restrict__ out0, float* __restrict__ out1,
    float* __restrict__ out2)
{
  const int g = blockIdx.x;
  const int tid = threadIdx.x;
  const int wv = tid >> 6;            // 0..3
  const int lane = tid & 63;          // 0..63
  const int row = (g << 8) | tid;     // this lane's W2 row

  // W2 row -> 128 fp32 regs
  float w[TMPD];
  {
    const float4* wr = (const float4*)(W2 + (size_t)row * TMPD);
    #pragma unroll
    for (int c = 0; c < TMPD / 4; ++c) {
      float4 v = wr[c];
      w[4 * c + 0] = v.x; w[4 * c + 1] = v.y; w[4 * c + 2] = v.z; w[4 * c + 3] = v.w;
    }
  }
  const float br = b2v[row];

  __shared__ __align__(16) float hbuf[WPG][TMPD];  // per-wave private h
  __shared__ u64 ckey[WPG];                        // intra-wg key drop

  if (tid < WPG) ckey[tid] = 0ull;    // kill stale/garbage tags
  __syncthreads();                    // once, outside the hot loop

  int cur = init_idx[0];
  float2 u2 = *(const float2*)(U + 2 * lane);                       // U[0]
  float2 c2 = *(const float2*)(C + (size_t)cur * TMPD + 2 * lane);  // C[init]
  float2 e2 = {0.f, 0.f};                                           // out1 pipeline

  for (int t = 0; t < TT; ++t) {
    const u64 tg = tag_of(t);

    // h = leaky_relu(U[t] + C[cur]) -> this wave's private LDS copy
    float hx = u2.x + c2.x, hy = u2.y + c2.y;
    float2 h2 = { (hx > 0.f) ? hx : 0.01f * hx,
                  (hy > 0.f) ? hy : 0.01f * hy };
    *(float2*)(&hbuf[wv][2 * lane]) = h2;
    u2 = *(const float2*)(U + (size_t)(t + 1) * TMPD + 2 * lane);   // prefetch
    __builtin_amdgcn_wave_barrier();  // compiler fence; HW: same-wave LDS is in-order

    // logit = b2[row] + w . h
    float acc = br;
    #pragma unroll
    for (int k0 = 0; k0 < TMPD; k0 += 4) {
      float4 hv = *(const float4*)(&hbuf[wv][k0]);   // ds_read_b128 broadcast
      acc = fmaf(w[k0 + 0], hv.x, acc);
      acc = fmaf(w[k0 + 1], hv.y, acc);
      acc = fmaf(w[k0 + 2], hv.z, acc);
      acc = fmaf(w[k0 + 3], hv.w, acc);
    }
    float s = __expf(acc);

    // in-wave butterfly: max + sumexp
    float m = acc, S = s;
    #pragma unroll
    for (int off = 1; off < 64; off <<= 1) {
      m = fmaxf(m, __shfl_xor(m, off));
      S += __shfl_xor(S, off);
    }
    const u64 bal = __ballot(acc == m);
    const int win = __ffsll(bal) - 1;                // lowest lane = lowest row
    const int wrow = (g << 8) | (wv << 6) | win;

    u32 fb  = __float_as_uint(m);
    u32 ord = (fb & 0x80000000u) ? ~fb : (fb | 0x80000000u);
    u64 key = ((u64)ord << 32) | ((u64)(u32)(2047 - wrow) << 21)
            | ((u64)__half_as_ushort(__float2half(S)) << 5) | tg;

    if (lane == 0)
      __hip_atomic_store(&ckey[wv], key, __ATOMIC_RELAXED, __HIP_MEMORY_SCOPE_WORKGROUP);

    u64* base = slots + (size_t)t * NG;

    if (wv == 0) {
      // combine the 4 wave keys (tagged LDS poll), publish wg key
      u64 kc;
      do {
        kc = __hip_atomic_load(&ckey[lane & 3], __ATOMIC_RELAXED, __HIP_MEMORY_SCOPE_WORKGROUP);
      } while (!__all((int)((kc & 0x1Full) == tg)));
      u64 kmax = kc;
      float Sw = __half2float(__ushort_as_half((u16)((kc >> 5) & 0xFFFFull)));
      #pragma unroll
      for (int off = 1; off < 4; off <<= 1) {
        u64 ok = __shfl_xor(kmax, off);
        Sw += __shfl_xor(Sw, off);
        if (ok > kmax) kmax = ok;
      }
      u64 wgkey = (kmax & ~0x1FFFFFull)
                | ((u64)__half_as_ushort(__float2half(Sw)) << 5) | tg;
      if (lane == 0)
        __hip_atomic_store(base + g, wgkey, __ATOMIC_RELAXED, __HIP_MEMORY_SCOPE_AGENT);
    }

    // global poll: one coalesced 64B-line load per iteration
    u64 kq;
    do {
      kq = __hip_atomic_load(base + (lane & 7), __ATOMIC_RELAXED, __HIP_MEMORY_SCOPE_AGENT);
    } while (!__all((int)((kq & 0x1Full) == tg)));

    // winner: 3x shfl_xor max within each aligned 8-lane group
    u64 best = kq;
    #pragma unroll
    for (int off = 1; off < 8; off <<= 1) {
      u64 ok = __shfl_xor(best, off);
      if (ok > best) best = ok;
    }
    const int nidx = 2047 - (int)((best >> 21) & 0x7FF);

    // issue next-step C load NOW; tail overlaps its latency
    c2 = *(const float2*)(C + (size_t)nidx * TMPD + 2 * lane);

    float Sp = __half2float(__ushort_as_half((u16)((kq >> 5) & 0xFFFFull)));
    #pragma unroll
    for (int off = 1; off < 8; off <<= 1) Sp += __shfl_xor(Sp, off);
    const float lgS = __logf(Sp);

    out0[(size_t)t * VOC + row] = acc - lgS;

    if (g == 0) {
      if (wv == 1 && lane < EMBD / 2) {          // off the publisher wave
        if (t) *(float2*)(out1 + (size_t)(t - 1) * EMBD + 2 * lane) = e2;
        e2 = *(const float2*)(emb + (size_t)nidx * EMBD + 2 * lane);
      }
      if (tid == 128) out2[t] = (float)nidx;     // wave 2, lane 0
    }
    cur = nidx;
  }
  if (g == 0 && wv == 1 && lane < EMBD / 2)
    *(float2*)(out1 + (size_t)(TT - 1) * EMBD + 2 * lane) = e2;
}

// ---------------------------------------------------------------------------
extern "C" void kernel_launch(void* const* d_in, const int* in_sizes, int n_in,
                              void* d_out, int out_size, void* d_ws, size_t ws_size,
                              hipStream_t stream) {
  const float* x    = (const float*)d_in[0];   // [16384,256] f32
  const float* emb  = (const float*)d_in[1];   // [2048,16]   f32
  const float* W1   = (const float*)d_in[2];   // [128,272]   f32
  const float* b1   = (const float*)d_in[3];   // [128]       f32
  const float* W2   = (const float*)d_in[4];   // [2048,128]  f32
  const float* b2v  = (const float*)d_in[5];   // [2048]      f32
  const int*   init = (const int*)d_in[6];     // scalar int

  float* U    = (float*)((char*)d_ws + U_OFF_B);
  float* C    = (float*)((char*)d_ws + C_OFF_B);
  u64*   slot = (u64*)((char*)d_ws + SLOT_OFF_B);

  float* out0 = (float*)d_out;                                        // [T, 2048]
  float* out1 = (float*)d_out + (size_t)TT * VOC;                     // [T, 1, 16]
  float* out2 = (float*)d_out + (size_t)TT * VOC + (size_t)TT * EMBD; // [T]

  hipLaunchKernelGGL(prep_kernel, dim3(TT + VOC), dim3(128), 0, stream,
                     x, emb, W1, b1, U, C, slot);
  hipLaunchKernelGGL(seq_kernel, dim3(NG), dim3(256), 0, stream,
                     emb, W2, b2v, init, U, C, slot, out0, out1, out2);
}